// Round 1
// baseline (4159.943 us; speedup 1.0000x reference)
//
#include <hip/hip_runtime.h>

#define BATCH 64
#define SEQ   2048
#define HID   256

typedef _Float16 f16;
typedef __attribute__((ext_vector_type(8))) _Float16 f16x8;
typedef __attribute__((ext_vector_type(4))) float f32x4;

__device__ __forceinline__ float fast_sigmoid(float z) {
    // 1/(1+2^(-z*log2 e))
    return __builtin_amdgcn_rcpf(1.0f + __builtin_amdgcn_exp2f(-1.4426950408889634f * z));
}
__device__ __forceinline__ float fast_tanh(float z) {
    // 2*sigmoid(2z)-1
    return 2.0f * __builtin_amdgcn_rcpf(1.0f + __builtin_amdgcn_exp2f(-2.8853900817779268f * z)) - 1.0f;
}

#if __has_builtin(__builtin_amdgcn_sdot4)
__device__ __forceinline__ int dot4(int a, int b, int c) {
    return __builtin_amdgcn_sdot4(a, b, c, false);
}
#else
__device__ __forceinline__ int dot4(int a, int b, int c) {
#pragma unroll
    for (int i = 0; i < 4; ++i) {
        int ab = (a << (24 - 8 * i)) >> 24;
        int bb = (b << (24 - 8 * i)) >> 24;
        c += ab * bb;
    }
    return c;
}
#endif

// ---------------------------------------------------------------------------
// Phase 1: xU[m, 0:1024] = x[m, 0:256] @ [U_i|U_f|U_o|U_c] + bias, fp16 out.
// 64x64 output tile per block, 4 waves, MFMA 16x16x32 f16, K-loop of 8x32.
// ---------------------------------------------------------------------------
__global__ __launch_bounds__(256, 2) void xu_gemm(
    const float* __restrict__ x,
    const float* __restrict__ U0, const float* __restrict__ U1,
    const float* __restrict__ U2, const float* __restrict__ U3,
    const float* __restrict__ b0, const float* __restrict__ b1,
    const float* __restrict__ b2, const float* __restrict__ b3,
    f16* __restrict__ xU)
{
    // row stride 40 f16 = 80 B: 16B-aligned rows, 2-way-max bank aliasing (free)
    __shared__ f16 As[64][40];   // A[m][k]
    __shared__ f16 Bs[64][40];   // B^T: Bs[n][k]

    const int m0 = blockIdx.x * 64;
    const int n0 = blockIdx.y * 64;
    const int gate = n0 >> 8;          // 64-col block lies within one gate
    const int nc0 = n0 & 255;
    const float* U    = (gate == 0) ? U0 : (gate == 1) ? U1 : (gate == 2) ? U2 : U3;
    const float* bias = (gate == 0) ? b0 : (gate == 1) ? b1 : (gate == 2) ? b2 : b3;

    const int tid  = threadIdx.x;
    const int w    = tid >> 6;
    const int lane = tid & 63;
    const int arow = tid >> 2, acq = (tid & 3) * 8;   // A staging: 4 thr/row
    const int brow = tid >> 3, bcq = (tid & 7) * 8;   // B staging: 8 thr/row

    f32x4 acc[4];
#pragma unroll
    for (int i = 0; i < 4; ++i) acc[i] = (f32x4){0.f, 0.f, 0.f, 0.f};

    for (int kc = 0; kc < 8; ++kc) {
        const int k0 = kc * 32;
        // stage A tile [64 x 32] fp32 -> fp16 (coalesced 128B runs)
        {
            const float* src = x + (size_t)(m0 + arow) * 256 + k0 + acq;
            float4 v0 = *(const float4*)src;
            float4 v1 = *(const float4*)(src + 4);
            f16x8 h;
            h[0] = (f16)v0.x; h[1] = (f16)v0.y; h[2] = (f16)v0.z; h[3] = (f16)v0.w;
            h[4] = (f16)v1.x; h[5] = (f16)v1.y; h[6] = (f16)v1.z; h[7] = (f16)v1.w;
            *(f16x8*)&As[arow][acq] = h;
        }
        // stage B tile [32 x 64] transposed into Bs[n][k]
        {
            const float* src = U + (size_t)(k0 + brow) * 256 + nc0 + bcq;
            float4 v0 = *(const float4*)src;
            float4 v1 = *(const float4*)(src + 4);
            Bs[bcq + 0][brow] = (f16)v0.x;
            Bs[bcq + 1][brow] = (f16)v0.y;
            Bs[bcq + 2][brow] = (f16)v0.z;
            Bs[bcq + 3][brow] = (f16)v0.w;
            Bs[bcq + 4][brow] = (f16)v1.x;
            Bs[bcq + 5][brow] = (f16)v1.y;
            Bs[bcq + 6][brow] = (f16)v1.z;
            Bs[bcq + 7][brow] = (f16)v1.w;
        }
        __syncthreads();
        // A frag: m = lane&15 (+16*w), k = (lane>>4)*8 + j  (contiguous 16B)
        const int qk = (lane >> 4) * 8;
        f16x8 afrag = *(const f16x8*)&As[16 * w + (lane & 15)][qk];
#pragma unroll
        for (int nt = 0; nt < 4; ++nt) {
            // B frag: n = lane&15 (+16*nt), k = (lane>>4)*8 + j
            f16x8 bfrag = *(const f16x8*)&Bs[nt * 16 + (lane & 15)][qk];
            acc[nt] = __builtin_amdgcn_mfma_f32_16x16x32_f16(afrag, bfrag, acc[nt], 0, 0, 0);
        }
        __syncthreads();
    }
    // C/D: col = lane&15 (n), row = (lane>>4)*4 + reg (m)  [verified mapping]
    const int col = lane & 15, quad = lane >> 4;
#pragma unroll
    for (int nt = 0; nt < 4; ++nt) {
        const int n = n0 + nt * 16 + col;
        const float bv = bias[n & 255];
#pragma unroll
        for (int r = 0; r < 4; ++r) {
            const int m = m0 + 16 * w + quad * 4 + r;
            xU[(size_t)m * 1024 + n] = (f16)(acc[nt][r] + bv);
        }
    }
}

// ---------------------------------------------------------------------------
// Phase 2: sequential recurrence. 64 blocks (1 per batch), 256 threads.
// Thread j owns hidden index j: all 4 gate columns (int8 weights in VGPRs,
// 256 regs), c-state in register, h broadcast via 256B int8 LDS buffer.
// One barrier per step (double-buffered h).
// ---------------------------------------------------------------------------
__global__ __launch_bounds__(256, 1) void lstm_rec(
    const f16* __restrict__ xU,
    const float* __restrict__ V0, const float* __restrict__ V1,
    const float* __restrict__ V2, const float* __restrict__ V3,
    float* __restrict__ out)
{
    const int b = blockIdx.x;
    const int j = threadIdx.x;

    // quantize V columns j of all 4 gates: w = round(V * 2048), packed 4x int8
    int w[4][64];
#pragma unroll
    for (int g = 0; g < 4; ++g) {
        const float* vp = (g == 0) ? V0 : (g == 1) ? V1 : (g == 2) ? V2 : V3;
#pragma unroll
        for (int k4 = 0; k4 < 64; ++k4) {
            int packed = 0;
#pragma unroll
            for (int u = 0; u < 4; ++u) {
                float v = vp[(size_t)(k4 * 4 + u) * 256 + j];  // coalesced across j
                int q = __float2int_rn(v * 2048.0f);
                q = q > 127 ? 127 : (q < -127 ? -127 : q);
                packed |= (q & 0xFF) << (8 * u);
            }
            w[g][k4] = packed;
        }
    }

    __shared__ alignas(16) int hq[2][64];   // packed int8 h, double-buffered
    if (j < 64) { hq[0][j] = 0; hq[1][j] = 0; }
    float c_state = 0.0f;
    float h_last = 0.0f;
    const f16* xrow = xU + (size_t)b * SEQ * 1024;
    float* hrow = out + (size_t)b * SEQ * HID;
    __syncthreads();

    const float INVS = 1.0f / (127.0f * 2048.0f);

    // software-prefetch xU one step ahead (independent of recurrence)
    float xn0 = (float)xrow[0 * 256 + j];
    float xn1 = (float)xrow[1 * 256 + j];
    float xn2 = (float)xrow[2 * 256 + j];
    float xn3 = (float)xrow[3 * 256 + j];

    for (int t = 0; t < SEQ; ++t) {
        const int cur = t & 1, nxt = cur ^ 1;
        const float xc0 = xn0, xc1 = xn1, xc2 = xn2, xc3 = xn3;
        const int tn = (t + 1 < SEQ) ? t + 1 : t;
        xn0 = (float)xrow[tn * 1024 + 0 * 256 + j];
        xn1 = (float)xrow[tn * 1024 + 1 * 256 + j];
        xn2 = (float)xrow[tn * 1024 + 2 * 256 + j];
        xn3 = (float)xrow[tn * 1024 + 3 * 256 + j];

        int a0 = 0, a1 = 0, a2 = 0, a3 = 0;
#pragma unroll
        for (int k16 = 0; k16 < 16; ++k16) {
            int4 hv = *((const int4*)hq[cur] + k16);   // broadcast, conflict-free
            a0 = dot4(hv.x, w[0][k16 * 4 + 0], a0);
            a0 = dot4(hv.y, w[0][k16 * 4 + 1], a0);
            a0 = dot4(hv.z, w[0][k16 * 4 + 2], a0);
            a0 = dot4(hv.w, w[0][k16 * 4 + 3], a0);
            a1 = dot4(hv.x, w[1][k16 * 4 + 0], a1);
            a1 = dot4(hv.y, w[1][k16 * 4 + 1], a1);
            a1 = dot4(hv.z, w[1][k16 * 4 + 2], a1);
            a1 = dot4(hv.w, w[1][k16 * 4 + 3], a1);
            a2 = dot4(hv.x, w[2][k16 * 4 + 0], a2);
            a2 = dot4(hv.y, w[2][k16 * 4 + 1], a2);
            a2 = dot4(hv.z, w[2][k16 * 4 + 2], a2);
            a2 = dot4(hv.w, w[2][k16 * 4 + 3], a2);
            a3 = dot4(hv.x, w[3][k16 * 4 + 0], a3);
            a3 = dot4(hv.y, w[3][k16 * 4 + 1], a3);
            a3 = dot4(hv.z, w[3][k16 * 4 + 2], a3);
            a3 = dot4(hv.w, w[3][k16 * 4 + 3], a3);
        }
        const float zi = xc0 + (float)a0 * INVS;
        const float zf = xc1 + (float)a1 * INVS;
        const float zo = xc2 + (float)a2 * INVS;
        const float zc = xc3 + (float)a3 * INVS;
        const float ig = fast_sigmoid(zi);
        const float fg = fast_sigmoid(zf);
        const float og = fast_sigmoid(zo);
        const float gg = fast_tanh(zc);
        c_state = fg * c_state + ig * gg;
        const float hv = og * fast_tanh(c_state);
        h_last = hv;
        hrow[t * HID + j] = hv;                         // coalesced 1KB store
        ((char*)hq[nxt])[j] = (char)__float2int_rn(hv * 127.0f);
        __syncthreads();
    }
    // tail outputs: h_T then c_T
    out[(size_t)BATCH * SEQ * HID + (size_t)b * HID + j] = h_last;
    out[(size_t)BATCH * SEQ * HID + (size_t)BATCH * HID + (size_t)b * HID + j] = c_state;
}

extern "C" void kernel_launch(void* const* d_in, const int* in_sizes, int n_in,
                              void* d_out, int out_size, void* d_ws, size_t ws_size,
                              hipStream_t stream) {
    const float* x  = (const float*)d_in[0];
    const float* Ui = (const float*)d_in[1];
    const float* Vi = (const float*)d_in[2];
    const float* bi = (const float*)d_in[3];
    const float* Uf = (const float*)d_in[4];
    const float* Vf = (const float*)d_in[5];
    const float* bf = (const float*)d_in[6];
    const float* Uo = (const float*)d_in[7];
    const float* Vo = (const float*)d_in[8];
    const float* bo = (const float*)d_in[9];
    const float* Uc = (const float*)d_in[10];
    const float* Vc = (const float*)d_in[11];
    const float* bc = (const float*)d_in[12];

    f16* xU = (f16*)d_ws;   // [64*2048, 1024] fp16 = 256 MiB

    dim3 g1(2048, 16);   // (M/64, 4H/64)
    xu_gemm<<<g1, 256, 0, stream>>>(x, Ui, Uf, Uo, Uc, bi, bf, bo, bc, xU);
    lstm_rec<<<64, 256, 0, stream>>>(xU, Vi, Vf, Vo, Vc, (float*)d_out);
}

// Round 2
// 2513.678 us; speedup vs baseline: 1.6549x; 1.6549x over previous
//
#include <hip/hip_runtime.h>

#define BATCH 64
#define SEQ   2048
#define HID   256

typedef _Float16 f16;
typedef __attribute__((ext_vector_type(8))) _Float16 f16x8;
typedef __attribute__((ext_vector_type(4))) float f32x4;

// s_waitcnt immediates (gfx9 encoding: vm[3:0]|exp[6:4]|lgkm[11:8]|vm_hi[15:14])
#define WAITCNT_LGKM0_ONLY 0xC07F   // lgkmcnt(0), vmcnt=63, expcnt=7
#define WAITCNT_VM12       0x0F7C   // vmcnt(12), lgkmcnt=15, expcnt=7

__device__ __forceinline__ float fast_sigmoid(float z) {
    return __builtin_amdgcn_rcpf(1.0f + __builtin_amdgcn_exp2f(-1.4426950408889634f * z));
}
__device__ __forceinline__ float fast_tanh(float z) {
    return 2.0f * __builtin_amdgcn_rcpf(1.0f + __builtin_amdgcn_exp2f(-2.8853900817779268f * z)) - 1.0f;
}

#if __has_builtin(__builtin_amdgcn_sdot4)
__device__ __forceinline__ int dot4(int a, int b, int c) {
    return __builtin_amdgcn_sdot4(a, b, c, false);
}
#else
__device__ __forceinline__ int dot4(int a, int b, int c) {
#pragma unroll
    for (int i = 0; i < 4; ++i) {
        int ab = (a << (24 - 8 * i)) >> 24;
        int bb = (b << (24 - 8 * i)) >> 24;
        c += ab * bb;
    }
    return c;
}
#endif

// async global->LDS, 16B per lane; LDS dest = uniform base + lane*16
typedef __attribute__((address_space(3))) unsigned int lds_u32;
typedef __attribute__((address_space(1))) const unsigned int gbl_u32;
__device__ __forceinline__ void gload16(void* l, const void* g) {
    __builtin_amdgcn_global_load_lds((gbl_u32*)g, (lds_u32*)l, 16, 0, 0);
}

// ---------------------------------------------------------------------------
// Phase 1: xU[m,0:1024] = x[m,0:256] @ [U_i|U_f|U_o|U_c] + bias -> fp16.
// 128x128 tile, 256 threads (4 waves), MFMA 16x16x32 f16, K-chunks of 32.
// Same verified fragment/C-D layout as round 1, scaled up 4x MFMA/staging.
// ---------------------------------------------------------------------------
__global__ __launch_bounds__(256, 2) void xu_gemm(
    const float* __restrict__ x,
    const float* __restrict__ U0, const float* __restrict__ U1,
    const float* __restrict__ U2, const float* __restrict__ U3,
    const float* __restrict__ b0, const float* __restrict__ b1,
    const float* __restrict__ b2, const float* __restrict__ b3,
    f16* __restrict__ xU)
{
    __shared__ f16 As[128][40];   // A[m][k], stride 80B (16B-aligned rows)
    __shared__ f16 Bs[128][40];   // B^T: Bs[n][k]

    const int m0 = blockIdx.x * 128;
    const int n0 = blockIdx.y * 128;
    const int gate = n0 >> 8;          // 128-col block lies within one gate
    const int nc0 = n0 & 255;
    const float* U    = (gate == 0) ? U0 : (gate == 1) ? U1 : (gate == 2) ? U2 : U3;
    const float* bias = (gate == 0) ? b0 : (gate == 1) ? b1 : (gate == 2) ? b2 : b3;

    const int tid  = threadIdx.x;
    const int wv   = tid >> 6;
    const int lane = tid & 63;
    const int arow = tid >> 1, acq = (tid & 1) * 16;   // A staging: 2 thr/row
    const int brow = tid >> 3, bcq = (tid & 7) * 16;   // B staging: 8 thr/k-row

    f32x4 acc[2][8];
#pragma unroll
    for (int mt = 0; mt < 2; ++mt)
#pragma unroll
        for (int nt = 0; nt < 8; ++nt) acc[mt][nt] = (f32x4){0.f, 0.f, 0.f, 0.f};

    for (int kc = 0; kc < 8; ++kc) {
        const int k0 = kc * 32;
        // stage A tile [128 x 32] fp32 -> fp16
        {
            const float* src = x + (size_t)(m0 + arow) * 256 + k0 + acq;
            float4 v0 = *(const float4*)src;
            float4 v1 = *(const float4*)(src + 4);
            float4 v2 = *(const float4*)(src + 8);
            float4 v3 = *(const float4*)(src + 12);
            f16x8 h0, h1;
            h0[0] = (f16)v0.x; h0[1] = (f16)v0.y; h0[2] = (f16)v0.z; h0[3] = (f16)v0.w;
            h0[4] = (f16)v1.x; h0[5] = (f16)v1.y; h0[6] = (f16)v1.z; h0[7] = (f16)v1.w;
            h1[0] = (f16)v2.x; h1[1] = (f16)v2.y; h1[2] = (f16)v2.z; h1[3] = (f16)v2.w;
            h1[4] = (f16)v3.x; h1[5] = (f16)v3.y; h1[6] = (f16)v3.z; h1[7] = (f16)v3.w;
            *(f16x8*)&As[arow][acq] = h0;
            *(f16x8*)&As[arow][acq + 8] = h1;
        }
        // stage B tile [32 x 128] transposed into Bs[n][k]
        {
            const float* src = U + (size_t)(k0 + brow) * 256 + nc0 + bcq;
            float4 v0 = *(const float4*)src;
            float4 v1 = *(const float4*)(src + 4);
            float4 v2 = *(const float4*)(src + 8);
            float4 v3 = *(const float4*)(src + 12);
            Bs[bcq +  0][brow] = (f16)v0.x;  Bs[bcq +  1][brow] = (f16)v0.y;
            Bs[bcq +  2][brow] = (f16)v0.z;  Bs[bcq +  3][brow] = (f16)v0.w;
            Bs[bcq +  4][brow] = (f16)v1.x;  Bs[bcq +  5][brow] = (f16)v1.y;
            Bs[bcq +  6][brow] = (f16)v1.z;  Bs[bcq +  7][brow] = (f16)v1.w;
            Bs[bcq +  8][brow] = (f16)v2.x;  Bs[bcq +  9][brow] = (f16)v2.y;
            Bs[bcq + 10][brow] = (f16)v2.z;  Bs[bcq + 11][brow] = (f16)v2.w;
            Bs[bcq + 12][brow] = (f16)v3.x;  Bs[bcq + 13][brow] = (f16)v3.y;
            Bs[bcq + 14][brow] = (f16)v3.z;  Bs[bcq + 15][brow] = (f16)v3.w;
        }
        __syncthreads();
        const int qk = (lane >> 4) * 8;
        f16x8 afrag0 = *(const f16x8*)&As[wv * 32 +  0 + (lane & 15)][qk];
        f16x8 afrag1 = *(const f16x8*)&As[wv * 32 + 16 + (lane & 15)][qk];
#pragma unroll
        for (int nt = 0; nt < 8; ++nt) {
            f16x8 bfrag = *(const f16x8*)&Bs[nt * 16 + (lane & 15)][qk];
            acc[0][nt] = __builtin_amdgcn_mfma_f32_16x16x32_f16(afrag0, bfrag, acc[0][nt], 0, 0, 0);
            acc[1][nt] = __builtin_amdgcn_mfma_f32_16x16x32_f16(afrag1, bfrag, acc[1][nt], 0, 0, 0);
        }
        __syncthreads();
    }
    // C/D: col = lane&15 (n), row = (lane>>4)*4 + reg (m)
    const int col = lane & 15, quad = lane >> 4;
#pragma unroll
    for (int nt = 0; nt < 8; ++nt) {
        const int n = n0 + nt * 16 + col;
        const float bv = bias[n & 255];
#pragma unroll
        for (int mt = 0; mt < 2; ++mt) {
#pragma unroll
            for (int r = 0; r < 4; ++r) {
                const int m = m0 + wv * 32 + mt * 16 + quad * 4 + r;
                xU[(size_t)m * 1024 + n] = (f16)(acc[mt][nt][r] + bv);
            }
        }
    }
}

// ---------------------------------------------------------------------------
// Phase 2: recurrence. 64 blocks x 512 threads (2 waves/SIMD).
// Wave w, lane L: j = w*32 + (L&31), khalf = L>>5 (2-way K split -> 128
// weight VGPRs, no spill). shfl_xor(32) reduces the K halves.
// xU streamed through an 8-slot LDS ring via global_load_lds (wave 0,
// 7-step prefetch distance, vmcnt(12)). In-loop barrier = raw s_barrier
// with lgkmcnt(0) drain only -- no vmcnt(0) HBM round-trip per step.
// ---------------------------------------------------------------------------
__global__ __launch_bounds__(512, 2) void lstm_rec(
    const f16* __restrict__ xU,
    const float* __restrict__ V0, const float* __restrict__ V1,
    const float* __restrict__ V2, const float* __restrict__ V3,
    float* __restrict__ out)
{
    const int b    = blockIdx.x;
    const int tid  = threadIdx.x;
    const int wv   = tid >> 6;        // wave 0..7
    const int lane = tid & 63;
    const int jm   = lane & 31;
    const int kh   = lane >> 5;       // K half: 0 -> h[0:128), 1 -> h[128:256)
    const int j    = wv * 32 + jm;    // hidden index

    // quantize this thread's K-half of V columns j (4 gates): 32 packed words
    int w[4][32];
#pragma unroll
    for (int g = 0; g < 4; ++g) {
        const float* vp = (g == 0) ? V0 : (g == 1) ? V1 : (g == 2) ? V2 : V3;
#pragma unroll
        for (int kk = 0; kk < 32; ++kk) {
            int packed = 0;
#pragma unroll
            for (int u = 0; u < 4; ++u) {
                float v = vp[(size_t)((kh * 32 + kk) * 4 + u) * 256 + j];
                int q = __float2int_rn(v * 2048.0f);
                q = q > 127 ? 127 : (q < -127 ? -127 : q);
                packed |= (q & 0xFF) << (8 * u);
            }
            w[g][kk] = packed;
        }
    }

    __shared__ alignas(16) int hq[2][64];          // packed int8 h, dbuf
    __shared__ alignas(16) f16 xq[8][1024];        // xU ring, 2KB/slot
    if (tid < 64) { hq[0][tid] = 0; hq[1][tid] = 0; }

    const f16* xrow = xU + (size_t)b * SEQ * 1024;
    float* hrow = out + (size_t)b * SEQ * HID;

    // prefill ring slots 0..6 (wave 0 issues; __syncthreads drains vmcnt)
    if (wv == 0) {
#pragma unroll
        for (int s = 0; s < 7; ++s) {
            const f16* src = xrow + (size_t)s * 1024 + lane * 8;
            gload16(&xq[s][0], src);
            gload16(&xq[s][512], src + 512);
        }
    }
    float c_state = 0.0f, h_last = 0.0f;
    __syncthreads();

    const float INVS = 1.0f / (127.0f * 2048.0f);

    for (int t = 0; t < SEQ; ++t) {
        const int cur = t & 1, nxt = cur ^ 1;
        // issue next ring slot (7 steps ahead); vmcnt(12) proves slot t+1 done
        if (wv == 0) {
            const int tf = (t + 7 < SEQ) ? (t + 7) : (SEQ - 1);
            const int sl = (t + 7) & 7;
            const f16* src = xrow + (size_t)tf * 1024 + lane * 8;
            gload16(&xq[sl][0], src);
            gload16(&xq[sl][512], src + 512);
            __builtin_amdgcn_s_waitcnt(WAITCNT_VM12);
        }

        // load this thread's K-half of h (8 x b128, broadcast within halves)
        const int4* hp = (const int4*)&hq[cur][0] + kh * 8;
        int4 h0 = hp[0], h1 = hp[1], h2 = hp[2], h3 = hp[3];
        int4 h4 = hp[4], h5 = hp[5], h6 = hp[6], h7 = hp[7];

        int a0 = 0, a1 = 0, a2 = 0, a3 = 0;
#define DOT16(HV, I)                                                     \
        a0 = dot4(HV.x, w[0][I + 0], a0); a0 = dot4(HV.y, w[0][I + 1], a0); \
        a0 = dot4(HV.z, w[0][I + 2], a0); a0 = dot4(HV.w, w[0][I + 3], a0); \
        a1 = dot4(HV.x, w[1][I + 0], a1); a1 = dot4(HV.y, w[1][I + 1], a1); \
        a1 = dot4(HV.z, w[1][I + 2], a1); a1 = dot4(HV.w, w[1][I + 3], a1); \
        a2 = dot4(HV.x, w[2][I + 0], a2); a2 = dot4(HV.y, w[2][I + 1], a2); \
        a2 = dot4(HV.z, w[2][I + 2], a2); a2 = dot4(HV.w, w[2][I + 3], a2); \
        a3 = dot4(HV.x, w[3][I + 0], a3); a3 = dot4(HV.y, w[3][I + 1], a3); \
        a3 = dot4(HV.z, w[3][I + 2], a3); a3 = dot4(HV.w, w[3][I + 3], a3);
        DOT16(h0,  0) DOT16(h1,  4) DOT16(h2,  8) DOT16(h3, 12)
        DOT16(h4, 16) DOT16(h5, 20) DOT16(h6, 24) DOT16(h7, 28)
#undef DOT16

        // combine K halves (both halves end with identical full sums)
        a0 += __shfl_xor(a0, 32, 64);
        a1 += __shfl_xor(a1, 32, 64);
        a2 += __shfl_xor(a2, 32, 64);
        a3 += __shfl_xor(a3, 32, 64);

        const int sl = t & 7;
        const float zi = (float)xq[sl][0 * 256 + j] + (float)a0 * INVS;
        const float zf = (float)xq[sl][1 * 256 + j] + (float)a1 * INVS;
        const float zo = (float)xq[sl][2 * 256 + j] + (float)a2 * INVS;
        const float zc = (float)xq[sl][3 * 256 + j] + (float)a3 * INVS;
        const float ig = fast_sigmoid(zi);
        const float fg = fast_sigmoid(zf);
        const float og = fast_sigmoid(zo);
        const float gg = fast_tanh(zc);
        c_state = fg * c_state + ig * gg;
        const float hv = og * fast_tanh(c_state);
        h_last = hv;
        if (kh == 0) {
            hrow[t * HID + j] = hv;                 // fire-and-forget store
            ((char*)&hq[nxt][0])[j] = (char)__float2int_rn(hv * 127.0f);
        }
        // barrier: drain LDS ops only (no vmcnt(0) HBM round-trip)
        __builtin_amdgcn_s_waitcnt(WAITCNT_LGKM0_ONLY);
        __builtin_amdgcn_s_barrier();
    }
    if (kh == 0) {
        out[(size_t)BATCH * SEQ * HID + (size_t)b * HID + j] = h_last;
        out[(size_t)BATCH * SEQ * HID + (size_t)BATCH * HID + (size_t)b * HID + j] = c_state;
    }
}

extern "C" void kernel_launch(void* const* d_in, const int* in_sizes, int n_in,
                              void* d_out, int out_size, void* d_ws, size_t ws_size,
                              hipStream_t stream) {
    const float* x  = (const float*)d_in[0];
    const float* Ui = (const float*)d_in[1];
    const float* Vi = (const float*)d_in[2];
    const float* bi = (const float*)d_in[3];
    const float* Uf = (const float*)d_in[4];
    const float* Vf = (const float*)d_in[5];
    const float* bf = (const float*)d_in[6];
    const float* Uo = (const float*)d_in[7];
    const float* Vo = (const float*)d_in[8];
    const float* bo = (const float*)d_in[9];
    const float* Uc = (const float*)d_in[10];
    const float* Vc = (const float*)d_in[11];
    const float* bc = (const float*)d_in[12];

    f16* xU = (f16*)d_ws;   // [131072, 1024] fp16 = 256 MiB

    dim3 g1(1024, 8);   // (M/128, 4H/128)
    xu_gemm<<<g1, 256, 0, stream>>>(x, Ui, Uf, Uo, Uc, bi, bf, bo, bc, xU);
    lstm_rec<<<64, 512, 0, stream>>>(xU, Vi, Vf, Vo, Vc, (float*)d_out);
}